// Round 2
// baseline (128.262 us; speedup 1.0000x reference)
//
#include <hip/hip_runtime.h>

// Problem constants (from reference):
//   N_KV_HEADS=8, MAX_CONTEXT=8192, HEAD_DIM=128, N_NEW=16, dtype fp32
// Output = concat(kout, vout) flat, each (1,8,8192,128) fp32.
//
// Strategy (R1): split the clone-then-scatter into
//   (1) a branch-free streaming copy of both caches -> out   (134 MB traffic)
//   (2) a tiny scatter of the 16 new rows per head per cache (0.5 MB traffic)
// The old fused kernel put a 16-compare dependent chain + divergent branch in
// front of EVERY bulk-copy load; the bulk path (99.9996% of threads) is a pure
// memcpy and should run at copy BW (~6.3 TB/s) like the harness fills do.
//
// R2 fix: __builtin_nontemporal_* requires a native vector type, not
// HIP_vector_type<float,4> -> use clang ext_vector_type(4) float.
//
// Layout in float4 units:
//   per-cache float4 count: 8*8192*(128/4) = 2^21 ; total out = 2^22
//   j (within one cache): h = j>>18, s = (j>>5)&8191, d4 = j&31

#define NNEW 16

typedef float f32x4 __attribute__((ext_vector_type(4)));

__global__ __launch_bounds__(256) void kv_copy_kernel(
    const f32x4* __restrict__ kcache,
    const f32x4* __restrict__ vcache,
    f32x4* __restrict__ out)
{
    const unsigned int i = blockIdx.x * 256u + threadIdx.x;   // [0, 2^22)
    const unsigned int j = i & ((1u << 21) - 1u);
    // uniform per wave (i>>21 constant within a block)
    const f32x4* __restrict__ src = (i >> 21) ? vcache : kcache;
    // Streaming data, never re-read from out; skip L2 pollution.
    f32x4 val = __builtin_nontemporal_load(&src[j]);
    __builtin_nontemporal_store(val, &out[i]);
}

__global__ __launch_bounds__(256) void kv_scatter_kernel(
    const int* __restrict__ pos,
    const f32x4* __restrict__ knew,
    const f32x4* __restrict__ vnew,
    f32x4* __restrict__ out)
{
    // 2 caches * 8 heads * 16 new rows * 32 float4s = 8192 threads
    const unsigned int t  = blockIdx.x * 256u + threadIdx.x;  // [0, 8192)
    const unsigned int d4 = t & 31u;
    const unsigned int n  = (t >> 5) & 15u;
    const unsigned int h  = (t >> 9) & 7u;
    const unsigned int c  = t >> 12;                           // 0=k, 1=v

    const int s = pos[n];

    // Sequential-assignment semantics for duplicate pos: LAST write wins.
    // Skip this row if any later n' targets the same position (avoids a
    // nondeterministic same-address race between two scatter lanes).
    bool skip = false;
#pragma unroll
    for (int m = 0; m < NNEW; ++m) {
        if (m > (int)n && pos[m] == s) skip = true;
    }
    if (skip) return;

    const f32x4* __restrict__ src = c ? vnew : knew;
    // new tensor layout: (1, 8, 16, 128) -> (h*16 + n)*32 + d4 float4s
    out[(c << 21) + (h << 18) + ((unsigned)s << 5) + d4] =
        src[(h * NNEW + n) * 32u + d4];
}

extern "C" void kernel_launch(void* const* d_in, const int* in_sizes, int n_in,
                              void* d_out, int out_size, void* d_ws, size_t ws_size,
                              hipStream_t stream) {
    // setup_inputs order: pos_ids, k, v, k_cache, v_cache
    const int*   pos    = (const int*)  d_in[0];
    const f32x4* knew   = (const f32x4*)d_in[1];
    const f32x4* vnew   = (const f32x4*)d_in[2];
    const f32x4* kcache = (const f32x4*)d_in[3];
    const f32x4* vcache = (const f32x4*)d_in[4];
    f32x4*       out    = (f32x4*)d_out;

    // Bulk copy: 2^22 float4s, 1 per thread, 256 threads/block -> 16384 blocks.
    kv_copy_kernel<<<(1u << 22) / 256u, 256, 0, stream>>>(kcache, vcache, out);
    // Scatter the 16 new rows (stream-ordered after the copy).
    kv_scatter_kernel<<<8192 / 256, 256, 0, stream>>>(pos, knew, vnew, out);
}

// Round 3
// 121.384 us; speedup vs baseline: 1.0567x; 1.0567x over previous
//
#include <hip/hip_runtime.h>

// Problem constants (from reference):
//   N_KV_HEADS=8, MAX_CONTEXT=8192, HEAD_DIM=128, N_NEW=16, dtype fp32
// Output = concat(kout, vout) flat, each (1,8,8192,128) fp32.
//
// R3: single fused kernel (R2's split+nontemporal regressed: +1 dispatch drain
// and nt bypassing an L3 that likely holds the 67MB of inputs). Amortize the
// per-element overhead instead: each thread handles 4 float4s (64 B) of ONE
// row, so the 16-compare pos match + index math is paid per-64B not per-16B,
// and 4 independent load/store pairs are in flight per thread.
//
// Layout in float4 units:
//   per-cache float4 count: 8*8192*32 = 2^21 ; total out = 2^22
//   thread t in [0, 2^20): c = t>>19 (0=k,1=v), jb = t & (2^19-1)
//     row r = jb>>3 (r = h*8192 + s), group g = jb&7
//     covers float4s  r*32 + g + {0,8,16,24}
//   Wave pattern per access: 8-lane groups read 128 B contiguous segments,
//   8 consecutive rows per wave -> 8 x 128 B segments, fully coalescible.

#define NNEW 16

typedef float f32x4 __attribute__((ext_vector_type(4)));

__global__ __launch_bounds__(256) void kv_update_kernel(
    const int* __restrict__ pos,
    const f32x4* __restrict__ knew,
    const f32x4* __restrict__ vnew,
    const f32x4* __restrict__ kcache,
    const f32x4* __restrict__ vcache,
    f32x4* __restrict__ out)
{
    const unsigned int t  = blockIdx.x * 256u + threadIdx.x;  // [0, 2^20)
    const unsigned int c  = t >> 19;                          // 0=k, 1=v
    const unsigned int jb = t & ((1u << 19) - 1u);
    const unsigned int r  = jb >> 3;        // row in [0, 65536) = h*8192 + s
    const unsigned int g  = jb & 7u;        // float4 group within row
    const unsigned int h  = r >> 13;        // head 0..7
    const int          s  = (int)(r & 8191u);  // seq position

    // pos is wave-uniform -> scalar loads through constant cache.
    // Last match wins => sequential-assignment semantics for dup indices.
    int match = -1;
#pragma unroll
    for (int n = 0; n < NNEW; ++n) {
        if (pos[n] == s) match = n;
    }

    const f32x4* __restrict__ src;
    unsigned int srcbase;
    if (match >= 0) {
        src = c ? vnew : knew;
        // new tensor layout: (1, 8, 16, 128) -> (h*16 + n)*32 float4s per row
        srcbase = (h * NNEW + (unsigned)match) * 32u + g;
    } else {
        src = c ? vcache : kcache;
        srcbase = r * 32u + g;
    }

    const unsigned int outbase = (c << 21) + r * 32u + g;

    // 4 independent 16 B loads, then 4 independent stores (same row).
    f32x4 v0 = src[srcbase];
    f32x4 v1 = src[srcbase + 8u];
    f32x4 v2 = src[srcbase + 16u];
    f32x4 v3 = src[srcbase + 24u];
    out[outbase]       = v0;
    out[outbase + 8u]  = v1;
    out[outbase + 16u] = v2;
    out[outbase + 24u] = v3;
}

extern "C" void kernel_launch(void* const* d_in, const int* in_sizes, int n_in,
                              void* d_out, int out_size, void* d_ws, size_t ws_size,
                              hipStream_t stream) {
    // setup_inputs order: pos_ids, k, v, k_cache, v_cache
    const int*   pos    = (const int*)  d_in[0];
    const f32x4* knew   = (const f32x4*)d_in[1];
    const f32x4* vnew   = (const f32x4*)d_in[2];
    const f32x4* kcache = (const f32x4*)d_in[3];
    const f32x4* vcache = (const f32x4*)d_in[4];
    f32x4*       out    = (f32x4*)d_out;

    // 2^20 threads, 64 B each; 256 threads/block -> 4096 blocks.
    kv_update_kernel<<<(1u << 20) / 256u, 256, 0, stream>>>(
        pos, knew, vnew, kcache, vcache, out);
}